// Round 15
// baseline (339.868 us; speedup 1.0000x reference)
//
#include <hip/hip_runtime.h>
#include <hip/hip_bf16.h>

using bf16 = __hip_bfloat16;

#define NA 50000
#define NE 600000

typedef __attribute__((ext_vector_type(8))) short short8;
typedef __attribute__((ext_vector_type(4))) float f32x4;

// ---- ws layout (BYTE offsets). Total ~74.5 MB (< proven-safe 81.6 MB) ----
#define HBUF_B   0u            // bf16 50000x256                      25.6 MB
#define FS_B     25600000u     // bf16 2 x 50000x128                  25.6 MB
#define EL_B     51200000u     // f32 4 x 200,000: el_gt, er_gt, el_uav, er_uav
#define RECS_B   54400000u     // uint4 1.2M edge records {src,ee bf16x4,pad} 19.2 MB
#define CNT_B    73600000u     // u32 100k histogram / cursor          0.4 MB
#define ROW_B    74000000u     // u32 100001 row offsets
#define TOPS_B   74400016u     // u32 128
#define FLAG_B   74400528u     // int dtype flag
#define WST_GT_B 74400544u     // bf16 128x64 transposed W_src_gt     16 KB
#define WST_UAV_B 74416928u    // bf16 128x64                         16 KB
#define WRT_B    74433312u     // bf16 256x64 transposed [Wres_gt|Wres_uav]
#define WFT_B    74466080u     // bf16 128x256 transposed W_f         64 KB
#define ELT_GT_B 74531616u     // bf16 16x64 el-weights gt (rows 4-15 zero)
#define ELT_UAV_B 74533664u    // bf16 16x64
#define ERT_B    74535712u     // bf16 16x64 er gt rows0-3, uav rows4-7, 8-15 zero
#define WS_BYTES 74537760u

__device__ __forceinline__ float b2f(bf16 v) { return __bfloat162float(v); }

__device__ __forceinline__ float ldf(const void* p, size_t i, int f32) {
    return f32 ? ((const float*)p)[i] : b2f(((const bf16*)p)[i]);
}

__device__ __forceinline__ unsigned short f2bs(float v) {
    bf16 t = __float2bfloat16(v);
    return *(unsigned short*)&t;
}

__device__ __forceinline__ float lrelu_exp(float v) {
    v = v > 0.f ? v : 0.2f * v;
    return __expf(v);
}

__device__ __forceinline__ unsigned int pack_bf16x2(float a, float b) {
    return (unsigned int)f2bs(a) | ((unsigned int)f2bs(b) << 16);
}

__device__ __forceinline__ float lo_f(unsigned int u) { return __uint_as_float(u << 16); }
__device__ __forceinline__ float hi_f(unsigned int u) { return __uint_as_float(u & 0xffff0000u); }

__device__ __forceinline__ short8 ldfrag8(const void* p, size_t off, int f32) {
    if (!f32) return *(const short8*)((const unsigned short*)p + off);
    union { short8 s; unsigned int u[4]; } r;
    const float* fp = (const float*)p + off;
#pragma unroll
    for (int j = 0; j < 4; ++j) r.u[j] = pack_bf16x2(fp[2 * j], fp[2 * j + 1]);
    return r.s;
}

__device__ int probe_f32(const void* x0) {
    __shared__ int cnt;
    if (threadIdx.x == 0) cnt = 0;
    __syncthreads();
    const bf16* p = (const bf16*)x0;
    int bad = 0;
    for (int i = threadIdx.x; i < 1024; i += 256) {
        float av = fabsf(b2f(p[i]));
        if (!(av <= 1e6f)) bad++;
    }
    if (bad) atomicAdd(&cnt, bad);
    __syncthreads();
    return cnt > 8;
}

// prep (+fused dst histogram): blocks 0-20 convert/transpose weights to bf16
// tables, fold attn weights, write flag + sentinel; blocks >= 21 histogram dst.
__global__ void HeteroVisionConv_29703993819529_kernel(
    const void* x0,
    const void* Wsg, const void* alg, const void* Wdg, const void* arg_,
    const void* Wsu, const void* alu, const void* Wdu, const void* aru,
    const void* Wrg, const void* Wru, const void* Wf,
    const int* dg, const int* du, unsigned int* cnt,
    unsigned short* wsT_gt, unsigned short* wsT_uav, unsigned short* wrT,
    unsigned short* wfT, unsigned short* elT_gt, unsigned short* elT_uav,
    unsigned short* erT,
    int* flag, unsigned int* outp, long sent) {
    int b = blockIdx.x, t = threadIdx.x;
    if (b >= 21) {  // histogram: 4 edges/thread via int4
        int idx = (b - 21) * 256 + t;
        if (idx >= 300000) return;
        int g = idx >= 150000;
        int e = (idx - g * 150000) * 4;
        int4 d4 = *(const int4*)((g ? du : dg) + e);
        unsigned int* c = cnt + g * NA;
        atomicAdd(&c[d4.x], 1u);
        atomicAdd(&c[d4.y], 1u);
        atomicAdd(&c[d4.z], 1u);
        atomicAdd(&c[d4.w], 1u);
        return;
    }
    int f32 = probe_f32(x0);
    if (b == 20) {
        if (t == 0) { flag[0] = f32; outp[sent] = 0x447A447Au; }
        return;
    }
    if (b < 8) {               // WfT rows [b*16, b*16+16)
        for (int i = t; i < 16 * 256; i += 256) {
            int n = b * 16 + (i >> 8), k = i & 255;
            wfT[n * 256 + k] = f2bs(ldf(Wf, (size_t)k * 128 + n, f32));
        }
    } else if (b < 12) {       // WrT rows [(b-8)*64, +64)
        for (int i = t; i < 64 * 64; i += 256) {
            int n = (b - 8) * 64 + (i >> 6), k = i & 63;
            float v = (n < 128) ? ldf(Wrg, (size_t)k * 128 + n, f32)
                                : ldf(Wru, (size_t)k * 128 + (n - 128), f32);
            wrT[n * 64 + k] = f2bs(v);
        }
    } else if (b < 14) {       // WsT_gt halves
        for (int i = t; i < 64 * 64; i += 256) {
            int n = (b - 12) * 64 + (i >> 6), k = i & 63;
            wsT_gt[n * 64 + k] = f2bs(ldf(Wsg, (size_t)k * 128 + n, f32));
        }
    } else if (b < 16) {       // WsT_uav halves
        for (int i = t; i < 64 * 64; i += 256) {
            int n = (b - 14) * 64 + (i >> 6), k = i & 63;
            wsT_uav[n * 64 + k] = f2bs(ldf(Wsu, (size_t)k * 128 + n, f32));
        }
    } else {                   // fold attn weights, m = b-16
        int m = b - 16;
        const void* Wm = (m == 0) ? Wsg : (m == 1) ? Wdg : (m == 2) ? Wsu : Wdu;
        const void* Am = (m == 0) ? alg : (m == 1) ? arg_ : (m == 2) ? alu : aru;
        int k = t >> 2, h = t & 3;
        float a = 0.f;
        for (int d = 0; d < 32; ++d)
            a += ldf(Wm, (size_t)k * 128 + h * 32 + d, f32) *
                 ldf(Am, (size_t)h * 32 + d, f32);
        unsigned short v = f2bs(a);
        if (m == 0) {
            elT_gt[h * 64 + k] = v;
            for (int i = t; i < 12 * 64; i += 256) elT_gt[(4 + (i >> 6)) * 64 + (i & 63)] = 0;
        } else if (m == 2) {
            elT_uav[h * 64 + k] = v;
            for (int i = t; i < 12 * 64; i += 256) elT_uav[(4 + (i >> 6)) * 64 + (i & 63)] = 0;
        } else if (m == 1) {
            erT[h * 64 + k] = v;
        } else {
            erT[(4 + h) * 64 + k] = v;
            for (int i = t; i < 8 * 64; i += 256) erT[(8 + (i >> 6)) * 64 + (i & 63)] = 0;
        }
    }
}

// MFMA fs = x_src @ W_src + fused el GEMV. LDS-staged Bt (u16 copy from table).
__global__ void node_fs_k(const void* xg, const void* xu,
                          const unsigned short* wsT_gt, const unsigned short* wsT_uav,
                          const unsigned short* elT_gt, const unsigned short* elT_uav,
                          float* elbase, bf16* fs, const int* flag) {
    int f32 = *flag;
    int bx = blockIdx.x, g = bx / 782, b = bx % 782;
    const void* A = g ? xu : xg;
    const unsigned short* WT = g ? wsT_uav : wsT_gt;
    const unsigned short* ET = g ? elT_uav : elT_gt;
    float* elout = elbase + (g ? 400000 : 0);
    bf16* out = fs + (size_t)g * NA * 128;
    __shared__ unsigned short Bt[128 * 72];  // 18 KB, pad 8
    int t = threadIdx.x;
    for (int i = t * 8; i < 128 * 64; i += 256 * 8) {
        short8 v = *(const short8*)(WT + i);
        int n = i >> 6, k = i & 63;
        *(short8*)&Bt[n * 72 + k] = v;
    }
    __syncthreads();
    int lane = t & 63, w = t >> 6;
    int m = lane & 15, quad = lane >> 4;
    int row = b * 64 + w * 16 + m;
    int rowc = row < NA ? row : NA - 1;
    short8 a0 = ldfrag8(A, (size_t)rowc * 64 + quad * 8, f32);
    short8 a1 = ldfrag8(A, (size_t)rowc * 64 + 32 + quad * 8, f32);
    f32x4 acc[8];
#pragma unroll
    for (int nt = 0; nt < 8; ++nt) acc[nt] = (f32x4){0.f, 0.f, 0.f, 0.f};
#pragma unroll
    for (int nt = 0; nt < 8; ++nt) {
        short8 b0 = *(const short8*)&Bt[(nt * 16 + m) * 72 + quad * 8];
        short8 b1 = *(const short8*)&Bt[(nt * 16 + m) * 72 + 32 + quad * 8];
        acc[nt] = __builtin_amdgcn_mfma_f32_16x16x32_bf16(a0, b0, acc[nt], 0, 0, 0);
        acc[nt] = __builtin_amdgcn_mfma_f32_16x16x32_bf16(a1, b1, acc[nt], 0, 0, 0);
    }
    f32x4 eacc = (f32x4){0.f, 0.f, 0.f, 0.f};
    {
        short8 e0 = *(const short8*)&ET[m * 64 + quad * 8];
        short8 e1 = *(const short8*)&ET[m * 64 + 32 + quad * 8];
        eacc = __builtin_amdgcn_mfma_f32_16x16x32_bf16(a0, e0, eacc, 0, 0, 0);
        eacc = __builtin_amdgcn_mfma_f32_16x16x32_bf16(a1, e1, eacc, 0, 0, 0);
    }
    int srow = b * 64 + w * 16 + quad * 4;
#pragma unroll
    for (int nt = 0; nt < 8; ++nt) {
#pragma unroll
        for (int r = 0; r < 4; ++r) {
            int rr = srow + r;
            if (rr < NA) out[(size_t)rr * 128 + nt * 16 + m] = __float2bfloat16(acc[nt][r]);
        }
    }
    if (m < 4) {
#pragma unroll
        for (int r = 0; r < 4; ++r) {
            int rr = srow + r;
            if (rr < NA) elout[(size_t)rr * 4 + m] = eacc[r];
        }
    }
}

// MFMA res: hbuf = x_ag @ [Wres_gt|Wres_uav] + bias, fused er GEMVs. LDS-staged.
__global__ void res_k(const void* xa, const unsigned short* wrT,
                      const unsigned short* erT,
                      const void* bg, const void* bu,
                      float* elbase, bf16* hbuf, const int* flag) {
    int f32 = *flag;
    int b = blockIdx.x;
    __shared__ unsigned short Bt[256 * 72];  // 36 KB
    __shared__ float bl[256];
    int t = threadIdx.x;
    for (int i = t * 8; i < 256 * 64; i += 256 * 8) {
        short8 v = *(const short8*)(wrT + i);
        int n = i >> 6, k = i & 63;
        *(short8*)&Bt[n * 72 + k] = v;
    }
    bl[t] = (t < 128) ? ldf(bg, t, f32) : ldf(bu, t - 128, f32);
    __syncthreads();
    int lane = t & 63, w = t >> 6;
    int m = lane & 15, quad = lane >> 4;
    int row = b * 64 + w * 16 + m;
    int rowc = row < NA ? row : NA - 1;
    short8 a0 = ldfrag8(xa, (size_t)rowc * 64 + quad * 8, f32);
    short8 a1 = ldfrag8(xa, (size_t)rowc * 64 + 32 + quad * 8, f32);
    f32x4 acc[16];
#pragma unroll
    for (int nt = 0; nt < 16; ++nt) acc[nt] = (f32x4){0.f, 0.f, 0.f, 0.f};
#pragma unroll
    for (int nt = 0; nt < 16; ++nt) {
        short8 b0 = *(const short8*)&Bt[(nt * 16 + m) * 72 + quad * 8];
        short8 b1 = *(const short8*)&Bt[(nt * 16 + m) * 72 + 32 + quad * 8];
        acc[nt] = __builtin_amdgcn_mfma_f32_16x16x32_bf16(a0, b0, acc[nt], 0, 0, 0);
        acc[nt] = __builtin_amdgcn_mfma_f32_16x16x32_bf16(a1, b1, acc[nt], 0, 0, 0);
    }
    f32x4 eacc = (f32x4){0.f, 0.f, 0.f, 0.f};
    {
        short8 e0 = *(const short8*)&erT[m * 64 + quad * 8];
        short8 e1 = *(const short8*)&erT[m * 64 + 32 + quad * 8];
        eacc = __builtin_amdgcn_mfma_f32_16x16x32_bf16(a0, e0, eacc, 0, 0, 0);
        eacc = __builtin_amdgcn_mfma_f32_16x16x32_bf16(a1, e1, eacc, 0, 0, 0);
    }
    int srow = b * 64 + w * 16 + quad * 4;
#pragma unroll
    for (int nt = 0; nt < 16; ++nt) {
        int col = nt * 16 + m;
#pragma unroll
        for (int r = 0; r < 4; ++r) {
            int rr = srow + r;
            if (rr < NA)
                hbuf[(size_t)rr * 256 + col] = __float2bfloat16(acc[nt][r] + bl[col]);
        }
    }
    if (m < 8) {
        float* ero = (m < 4) ? (elbase + 200000) : (elbase + 600000);
        int mm = m & 3;
#pragma unroll
        for (int r = 0; r < 4; ++r) {
            int rr = srow + r;
            if (rr < NA) ero[(size_t)rr * 4 + mm] = eacc[r];
        }
    }
}

__global__ void scan1_k(const unsigned int* cnt, unsigned int* row, unsigned int* tops) {
    __shared__ unsigned int sh[256];
    int b = blockIdx.x, t = threadIdx.x;
    int base = b * 1024 + t * 4;
    unsigned int v[4];
    for (int j = 0; j < 4; ++j) v[j] = (base + j < 100000) ? cnt[base + j] : 0u;
    unsigned int s = v[0] + v[1] + v[2] + v[3];
    sh[t] = s;
    __syncthreads();
    for (int off = 1; off < 256; off <<= 1) {
        unsigned int x = (t >= off) ? sh[t - off] : 0u;
        __syncthreads();
        sh[t] += x;
        __syncthreads();
    }
    unsigned int run = sh[t] - s;
    for (int j = 0; j < 4; ++j) {
        if (base + j < 100000) row[base + j] = run;
        run += v[j];
    }
    if (t == 255) tops[b] = sh[255];
}

__global__ void scan2_k(unsigned int* tops, unsigned int* row) {
    __shared__ unsigned int sh[128];
    int t = threadIdx.x;
    unsigned int v = (t < 98) ? tops[t] : 0u;
    sh[t] = v;
    __syncthreads();
    for (int off = 1; off < 128; off <<= 1) {
        unsigned int x = (t >= off) ? sh[t - off] : 0u;
        __syncthreads();
        sh[t] += x;
        __syncthreads();
    }
    if (t < 98) tops[t] = sh[t] - v;
    if (t == 97) row[100000] = sh[97];
}

__global__ void scan3_k(unsigned int* row, const unsigned int* tops, unsigned int* cursor) {
    int b = blockIdx.x, t = threadIdx.x;
    unsigned int off = tops[b];
    for (int i = b * 1024 + t; i < b * 1024 + 1024; i += 256) {
        if (i < 100000) {
            unsigned int r = row[i] + off;
            row[i] = r;
            cursor[i] = r;
        }
    }
}

// CSR scatter v2: ONE edge per thread (was 4) — kills the 4-long
// atomic->store dependency chain and doubles occupancy headroom.
__global__ void scatter_k(const int* sg, const int* dg, const int* su, const int* du,
                          const float* elbase, unsigned int* cursor, uint4* recs) {
    int idx = blockIdx.x * 256 + threadIdx.x;
    if (idx >= 2 * NE) return;
    int g = idx >= NE;
    int e = idx - g * NE;
    int s = (g ? su : sg)[e];
    int d = (g ? du : dg)[e];
    const float4* el4 = (const float4*)(elbase + (g ? 400000 : 0));
    const float4* er4 = (const float4*)(elbase + (g ? 600000 : 200000));
    unsigned int pos = atomicAdd(&cursor[g * NA + d], 1u);
    float4 l = el4[s], r = er4[d];
    uint4 rec;
    rec.x = (unsigned int)s;
    rec.y = pack_bf16x2(lrelu_exp(l.x + r.x), lrelu_exp(l.y + r.y));
    rec.z = pack_bf16x2(lrelu_exp(l.z + r.z), lrelu_exp(l.w + r.w));
    rec.w = 0u;
    recs[pos] = rec;
}

// gather v4: one wave per (dst, graph), TWO edges per wave iteration.
// Lanes 0-31 take even edges, 32-63 odd; each lane covers 4 cols via one
// uint2 (8B) fs load. Half-wave partials merged with shfl_xor(32) at row end.
// Fused residual + relu RMW on hbuf.
__global__ void gather_k(const unsigned int* row, const uint4* recs,
                         const bf16* fs, bf16* hbuf) {
    int wid = (blockIdx.x * 256 + threadIdx.x) >> 6;
    int lane = threadIdx.x & 63;
    if (wid >= 2 * NA) return;
    int g = wid / NA, d = wid - g * NA;
    int eh = lane >> 5;        // which edge of the pair
    int sl = lane & 31;        // cols c = sl*4 .. sl*4+3
    int h = sl >> 3;           // head for these cols
    int hsel = h >> 1, hodd = h & 1;
    unsigned int start = row[g * NA + d];
    unsigned int end   = row[g * NA + d + 1];
    const uint2* fsw2 = (const uint2*)(fs + (size_t)g * NA * 128);

    float denom = 0.f, a0 = 0.f, a1 = 0.f, a2 = 0.f, a3 = 0.f;
    unsigned int i = start;
    for (; i + 8 <= end; i += 8) {       // 4 pairs = 8 edges
        uint4 rr[4];
        uint2 uu[4];
#pragma unroll
        for (int j = 0; j < 4; ++j) rr[j] = recs[i + 2 * j + eh];
#pragma unroll
        for (int j = 0; j < 4; ++j) uu[j] = fsw2[(size_t)rr[j].x * 32 + sl];
#pragma unroll
        for (int j = 0; j < 4; ++j) {
            unsigned int pp = hsel ? rr[j].z : rr[j].y;
            float e = hodd ? hi_f(pp) : lo_f(pp);
            denom += e;
            a0 += lo_f(uu[j].x) * e;
            a1 += hi_f(uu[j].x) * e;
            a2 += lo_f(uu[j].y) * e;
            a3 += hi_f(uu[j].y) * e;
        }
    }
    for (; i + 2 <= end; i += 2) {       // single pair
        uint4 rc = recs[i + eh];
        uint2 u = fsw2[(size_t)rc.x * 32 + sl];
        unsigned int pp = hsel ? rc.z : rc.y;
        float e = hodd ? hi_f(pp) : lo_f(pp);
        denom += e;
        a0 += lo_f(u.x) * e;
        a1 += hi_f(u.x) * e;
        a2 += lo_f(u.y) * e;
        a3 += hi_f(u.y) * e;
    }
    if (i < end) {                       // odd tail: only eh==0 half contributes
        uint4 rc = recs[i];
        uint2 u = fsw2[(size_t)rc.x * 32 + sl];
        unsigned int pp = hsel ? rc.z : rc.y;
        float e = hodd ? hi_f(pp) : lo_f(pp);
        if (eh) e = 0.f;
        denom += e;
        a0 += lo_f(u.x) * e;
        a1 += hi_f(u.x) * e;
        a2 += lo_f(u.y) * e;
        a3 += hi_f(u.y) * e;
    }
    // merge the two half-wave partials (same dst row, same cols)
    denom += __shfl_xor(denom, 32, 64);
    a0 += __shfl_xor(a0, 32, 64);
    a1 += __shfl_xor(a1, 32, 64);
    a2 += __shfl_xor(a2, 32, 64);
    a3 += __shfl_xor(a3, 32, 64);
    if (eh == 0) {
        float inv = (end > start) ? 1.f / denom : 0.f;
        a0 *= inv; a1 *= inv; a2 *= inv; a3 *= inv;
        uint2* hp = (uint2*)(hbuf + (size_t)d * 256 + g * 128) + sl;
        uint2 rv = *hp;
        float v0 = a0 + lo_f(rv.x);
        float v1 = a1 + hi_f(rv.x);
        float v2 = a2 + lo_f(rv.y);
        float v3 = a3 + hi_f(rv.y);
        v0 = v0 > 0.f ? v0 : 0.f;
        v1 = v1 > 0.f ? v1 : 0.f;
        v2 = v2 > 0.f ? v2 : 0.f;
        v3 = v3 > 0.f ? v3 : 0.f;
        uint2 o;
        o.x = pack_bf16x2(v0, v1);
        o.y = pack_bf16x2(v2, v3);
        *hp = o;
    }
}

// MFMA final: out = relu(hbuf @ W_f + b_f). LDS-staged per 64-k chunk.
__global__ void final_k(const bf16* hbuf, const unsigned short* wfT,
                        const void* bfp, void* outp, const int* flag) {
    int f32 = *flag;
    int b = blockIdx.x;
    __shared__ unsigned short Bt[128 * 72];  // 18 KB
    __shared__ float bl[128];
    int t = threadIdx.x;
    if (t < 128) bl[t] = ldf(bfp, t, f32);
    int lane = t & 63, w = t >> 6;
    int m = lane & 15, quad = lane >> 4;
    int row = b * 64 + w * 16 + m;
    int rowc = row < NA ? row : NA - 1;
    f32x4 acc[8];
#pragma unroll
    for (int nt = 0; nt < 8; ++nt) acc[nt] = (f32x4){0.f, 0.f, 0.f, 0.f};
    for (int kc = 0; kc < 4; ++kc) {
        __syncthreads();
        for (int i = t * 8; i < 128 * 64; i += 256 * 8) {
            int n = i >> 6, k = i & 63;
            short8 v = *(const short8*)(wfT + (size_t)n * 256 + kc * 64 + k);
            *(short8*)&Bt[n * 72 + k] = v;
        }
        __syncthreads();
        short8 a0 = *(const short8*)((const unsigned short*)hbuf +
                                     (size_t)rowc * 256 + kc * 64 + quad * 8);
        short8 a1 = *(const short8*)((const unsigned short*)hbuf +
                                     (size_t)rowc * 256 + kc * 64 + 32 + quad * 8);
#pragma unroll
        for (int nt = 0; nt < 8; ++nt) {
            short8 b0 = *(const short8*)&Bt[(nt * 16 + m) * 72 + quad * 8];
            short8 b1 = *(const short8*)&Bt[(nt * 16 + m) * 72 + 32 + quad * 8];
            acc[nt] = __builtin_amdgcn_mfma_f32_16x16x32_bf16(a0, b0, acc[nt], 0, 0, 0);
            acc[nt] = __builtin_amdgcn_mfma_f32_16x16x32_bf16(a1, b1, acc[nt], 0, 0, 0);
        }
    }
    int srow = b * 64 + w * 16 + quad * 4;
#pragma unroll
    for (int nt = 0; nt < 8; ++nt) {
        int col = nt * 16 + m;
        float bv = bl[col];
#pragma unroll
        for (int r = 0; r < 4; ++r) {
            int rr = srow + r;
            if (rr < NA) {
                float v = acc[nt][r] + bv;
                v = v > 0.f ? v : 0.f;
                if (f32) ((float*)outp)[(size_t)rr * 128 + col] = v;
                else ((bf16*)outp)[(size_t)rr * 128 + col] = __float2bfloat16(v);
            }
        }
    }
}

extern "C" void kernel_launch(void* const* d_in, const int* in_sizes, int n_in,
                              void* d_out, int out_size, void* d_ws, size_t ws_size,
                              hipStream_t stream) {
    const void* x_gt     = d_in[0];
    const void* x_uav    = d_in[1];
    const void* x_ag     = d_in[2];
    const int*  src_gt   = (const int*)d_in[3];
    const int*  dst_gt   = (const int*)d_in[4];
    const int*  src_uav  = (const int*)d_in[5];
    const int*  dst_uav  = (const int*)d_in[6];
    const void* Wsrc_gt  = d_in[7];
    const void* Wdst_gt  = d_in[8];
    const void* al_gt    = d_in[9];
    const void* ar_gt    = d_in[10];
    const void* Wres_gt  = d_in[11];
    const void* b_gt     = d_in[12];
    const void* Wsrc_uav = d_in[13];
    const void* Wdst_uav = d_in[14];
    const void* al_uav   = d_in[15];
    const void* ar_uav   = d_in[16];
    const void* Wres_uav = d_in[17];
    const void* b_uav    = d_in[18];
    const void* W_f      = d_in[19];
    const void* b_f      = d_in[20];

    char* wsb = (char*)d_ws;
    bf16* hbuf = (bf16*)(wsb + HBUF_B);
    bf16* fs = (bf16*)(wsb + FS_B);
    float* el = (float*)(wsb + EL_B);
    uint4* recs = (uint4*)(wsb + RECS_B);
    unsigned int* cnt = (unsigned int*)(wsb + CNT_B);
    unsigned int* row = (unsigned int*)(wsb + ROW_B);
    unsigned int* tops = (unsigned int*)(wsb + TOPS_B);
    int* flag = (int*)(wsb + FLAG_B);
    unsigned short* wsT_gt = (unsigned short*)(wsb + WST_GT_B);
    unsigned short* wsT_uav = (unsigned short*)(wsb + WST_UAV_B);
    unsigned short* wrT = (unsigned short*)(wsb + WRT_B);
    unsigned short* wfT = (unsigned short*)(wsb + WFT_B);
    unsigned short* elT_gt = (unsigned short*)(wsb + ELT_GT_B);
    unsigned short* elT_uav = (unsigned short*)(wsb + ELT_UAV_B);
    unsigned short* erT = (unsigned short*)(wsb + ERT_B);

    if (ws_size < (size_t)WS_BYTES) {
        hipMemsetAsync(d_out, 0x42, (size_t)out_size * 2, stream);
        return;
    }

    long sent = (long)out_size / 2 - 1;

    hipMemsetAsync(cnt, 0, 100000 * 4, stream);
    HeteroVisionConv_29703993819529_kernel<<<21 + 1172, 256, 0, stream>>>(
        x_gt, Wsrc_gt, al_gt, Wdst_gt, ar_gt, Wsrc_uav, al_uav, Wdst_uav, ar_uav,
        Wres_gt, Wres_uav, W_f, dst_gt, dst_uav, cnt,
        wsT_gt, wsT_uav, wrT, wfT, elT_gt, elT_uav, erT,
        flag, (unsigned int*)d_out, sent);
    node_fs_k<<<1564, 256, 0, stream>>>(x_gt, x_uav, wsT_gt, wsT_uav,
                                        elT_gt, elT_uav, el, fs, flag);
    res_k<<<782, 256, 0, stream>>>(x_ag, wrT, erT, b_gt, b_uav, el, hbuf, flag);
    scan1_k<<<98, 256, 0, stream>>>(cnt, row, tops);
    scan2_k<<<1, 128, 0, stream>>>(tops, row);
    scan3_k<<<98, 256, 0, stream>>>(row, tops, cnt);
    scatter_k<<<4688, 256, 0, stream>>>(src_gt, dst_gt, src_uav, dst_uav,
                                        el, cnt, recs);
    gather_k<<<25000, 256, 0, stream>>>(row, recs, fs, hbuf);
    final_k<<<782, 256, 0, stream>>>(hbuf, wfT, b_f, d_out, flag);
}

// Round 16
// 313.205 us; speedup vs baseline: 1.0851x; 1.0851x over previous
//
#include <hip/hip_runtime.h>
#include <hip/hip_bf16.h>

using bf16 = __hip_bfloat16;

#define NA 50000
#define NE 600000

typedef __attribute__((ext_vector_type(8))) short short8;
typedef __attribute__((ext_vector_type(4))) float f32x4;

// ---- ws layout (BYTE offsets). Total ~79.3 MB (< proven-safe 81.6 MB) ----
#define HBUF_B   0u            // bf16 50000x256                      25.6 MB
#define FS_B     25600000u     // bf16 2 x 50000x128                  25.6 MB
#define EL_B     51200000u     // f32 4 x 200,000: el_gt, er_gt, el_uav, er_uav
#define RECS_B   54400000u     // uint4 1.2M edge records {src,ee bf16x4,pad} 19.2 MB
#define CNT_B    73600000u     // u32 100k histogram                   0.4 MB
#define ROW_B    74000000u     // u32 100001 row offsets
#define TOPS_B   74400016u     // u32 128
#define FLAG_B   74400528u     // int dtype flag
#define WST_GT_B 74400544u     // bf16 128x64 transposed W_src_gt     16 KB
#define WST_UAV_B 74416928u    // bf16 128x64                         16 KB
#define WRT_B    74433312u     // bf16 256x64 transposed [Wres_gt|Wres_uav]
#define WFT_B    74466080u     // bf16 128x256 transposed W_f         64 KB
#define ELT_GT_B 74531616u     // bf16 16x64 el-weights gt (rows 4-15 zero)
#define ELT_UAV_B 74533664u    // bf16 16x64
#define ERT_B    74535712u     // bf16 16x64 er gt rows0-3, uav rows4-7, 8-15 zero
#define RANK_B   74537760u     // u32 1.2M per-edge rank within dst    4.8 MB
#define WS_BYTES 79337760u

__device__ __forceinline__ float b2f(bf16 v) { return __bfloat162float(v); }

__device__ __forceinline__ float ldf(const void* p, size_t i, int f32) {
    return f32 ? ((const float*)p)[i] : b2f(((const bf16*)p)[i]);
}

__device__ __forceinline__ unsigned short f2bs(float v) {
    bf16 t = __float2bfloat16(v);
    return *(unsigned short*)&t;
}

__device__ __forceinline__ float lrelu_exp(float v) {
    v = v > 0.f ? v : 0.2f * v;
    return __expf(v);
}

__device__ __forceinline__ unsigned int pack_bf16x2(float a, float b) {
    return (unsigned int)f2bs(a) | ((unsigned int)f2bs(b) << 16);
}

__device__ __forceinline__ float lo_f(unsigned int u) { return __uint_as_float(u << 16); }
__device__ __forceinline__ float hi_f(unsigned int u) { return __uint_as_float(u & 0xffff0000u); }

__device__ __forceinline__ short8 ldfrag8(const void* p, size_t off, int f32) {
    if (!f32) return *(const short8*)((const unsigned short*)p + off);
    union { short8 s; unsigned int u[4]; } r;
    const float* fp = (const float*)p + off;
#pragma unroll
    for (int j = 0; j < 4; ++j) r.u[j] = pack_bf16x2(fp[2 * j], fp[2 * j + 1]);
    return r.s;
}

__device__ int probe_f32(const void* x0) {
    __shared__ int cnt;
    if (threadIdx.x == 0) cnt = 0;
    __syncthreads();
    const bf16* p = (const bf16*)x0;
    int bad = 0;
    for (int i = threadIdx.x; i < 1024; i += 256) {
        float av = fabsf(b2f(p[i]));
        if (!(av <= 1e6f)) bad++;
    }
    if (bad) atomicAdd(&cnt, bad);
    __syncthreads();
    return cnt > 8;
}

// prep (+fused dst histogram WITH rank capture): blocks 0-20 convert weights;
// blocks >= 21 histogram dst and record each edge's rank (= atomic return).
__global__ void HeteroVisionConv_29703993819529_kernel(
    const void* x0,
    const void* Wsg, const void* alg, const void* Wdg, const void* arg_,
    const void* Wsu, const void* alu, const void* Wdu, const void* aru,
    const void* Wrg, const void* Wru, const void* Wf,
    const int* dg, const int* du, unsigned int* cnt, unsigned int* rank,
    unsigned short* wsT_gt, unsigned short* wsT_uav, unsigned short* wrT,
    unsigned short* wfT, unsigned short* elT_gt, unsigned short* elT_uav,
    unsigned short* erT,
    int* flag, unsigned int* outp, long sent) {
    int b = blockIdx.x, t = threadIdx.x;
    if (b >= 21) {  // histogram + rank: 4 edges/thread via int4
        int idx = (b - 21) * 256 + t;
        if (idx >= 300000) return;
        int g = idx >= 150000;
        int e = (idx - g * 150000) * 4;
        int4 d4 = *(const int4*)((g ? du : dg) + e);
        unsigned int* c = cnt + g * NA;
        uint4 r4;
        r4.x = atomicAdd(&c[d4.x], 1u);
        r4.y = atomicAdd(&c[d4.y], 1u);
        r4.z = atomicAdd(&c[d4.z], 1u);
        r4.w = atomicAdd(&c[d4.w], 1u);
        *(uint4*)(rank + (size_t)g * NE + e) = r4;
        return;
    }
    int f32 = probe_f32(x0);
    if (b == 20) {
        if (t == 0) { flag[0] = f32; outp[sent] = 0x447A447Au; }
        return;
    }
    if (b < 8) {               // WfT rows [b*16, b*16+16)
        for (int i = t; i < 16 * 256; i += 256) {
            int n = b * 16 + (i >> 8), k = i & 255;
            wfT[n * 256 + k] = f2bs(ldf(Wf, (size_t)k * 128 + n, f32));
        }
    } else if (b < 12) {       // WrT rows [(b-8)*64, +64)
        for (int i = t; i < 64 * 64; i += 256) {
            int n = (b - 8) * 64 + (i >> 6), k = i & 63;
            float v = (n < 128) ? ldf(Wrg, (size_t)k * 128 + n, f32)
                                : ldf(Wru, (size_t)k * 128 + (n - 128), f32);
            wrT[n * 64 + k] = f2bs(v);
        }
    } else if (b < 14) {       // WsT_gt halves
        for (int i = t; i < 64 * 64; i += 256) {
            int n = (b - 12) * 64 + (i >> 6), k = i & 63;
            wsT_gt[n * 64 + k] = f2bs(ldf(Wsg, (size_t)k * 128 + n, f32));
        }
    } else if (b < 16) {       // WsT_uav halves
        for (int i = t; i < 64 * 64; i += 256) {
            int n = (b - 14) * 64 + (i >> 6), k = i & 63;
            wsT_uav[n * 64 + k] = f2bs(ldf(Wsu, (size_t)k * 128 + n, f32));
        }
    } else {                   // fold attn weights, m = b-16
        int m = b - 16;
        const void* Wm = (m == 0) ? Wsg : (m == 1) ? Wdg : (m == 2) ? Wsu : Wdu;
        const void* Am = (m == 0) ? alg : (m == 1) ? arg_ : (m == 2) ? alu : aru;
        int k = t >> 2, h = t & 3;
        float a = 0.f;
        for (int d = 0; d < 32; ++d)
            a += ldf(Wm, (size_t)k * 128 + h * 32 + d, f32) *
                 ldf(Am, (size_t)h * 32 + d, f32);
        unsigned short v = f2bs(a);
        if (m == 0) {
            elT_gt[h * 64 + k] = v;
            for (int i = t; i < 12 * 64; i += 256) elT_gt[(4 + (i >> 6)) * 64 + (i & 63)] = 0;
        } else if (m == 2) {
            elT_uav[h * 64 + k] = v;
            for (int i = t; i < 12 * 64; i += 256) elT_uav[(4 + (i >> 6)) * 64 + (i & 63)] = 0;
        } else if (m == 1) {
            erT[h * 64 + k] = v;
        } else {
            erT[(4 + h) * 64 + k] = v;
            for (int i = t; i < 8 * 64; i += 256) erT[(8 + (i >> 6)) * 64 + (i & 63)] = 0;
        }
    }
}

// MFMA fs = x_src @ W_src + fused el GEMV. LDS-staged Bt (u16 copy from table).
__global__ void node_fs_k(const void* xg, const void* xu,
                          const unsigned short* wsT_gt, const unsigned short* wsT_uav,
                          const unsigned short* elT_gt, const unsigned short* elT_uav,
                          float* elbase, bf16* fs, const int* flag) {
    int f32 = *flag;
    int bx = blockIdx.x, g = bx / 782, b = bx % 782;
    const void* A = g ? xu : xg;
    const unsigned short* WT = g ? wsT_uav : wsT_gt;
    const unsigned short* ET = g ? elT_uav : elT_gt;
    float* elout = elbase + (g ? 400000 : 0);
    bf16* out = fs + (size_t)g * NA * 128;
    __shared__ unsigned short Bt[128 * 72];  // 18 KB, pad 8
    int t = threadIdx.x;
    for (int i = t * 8; i < 128 * 64; i += 256 * 8) {
        short8 v = *(const short8*)(WT + i);
        int n = i >> 6, k = i & 63;
        *(short8*)&Bt[n * 72 + k] = v;
    }
    __syncthreads();
    int lane = t & 63, w = t >> 6;
    int m = lane & 15, quad = lane >> 4;
    int row = b * 64 + w * 16 + m;
    int rowc = row < NA ? row : NA - 1;
    short8 a0 = ldfrag8(A, (size_t)rowc * 64 + quad * 8, f32);
    short8 a1 = ldfrag8(A, (size_t)rowc * 64 + 32 + quad * 8, f32);
    f32x4 acc[8];
#pragma unroll
    for (int nt = 0; nt < 8; ++nt) acc[nt] = (f32x4){0.f, 0.f, 0.f, 0.f};
#pragma unroll
    for (int nt = 0; nt < 8; ++nt) {
        short8 b0 = *(const short8*)&Bt[(nt * 16 + m) * 72 + quad * 8];
        short8 b1 = *(const short8*)&Bt[(nt * 16 + m) * 72 + 32 + quad * 8];
        acc[nt] = __builtin_amdgcn_mfma_f32_16x16x32_bf16(a0, b0, acc[nt], 0, 0, 0);
        acc[nt] = __builtin_amdgcn_mfma_f32_16x16x32_bf16(a1, b1, acc[nt], 0, 0, 0);
    }
    f32x4 eacc = (f32x4){0.f, 0.f, 0.f, 0.f};
    {
        short8 e0 = *(const short8*)&ET[m * 64 + quad * 8];
        short8 e1 = *(const short8*)&ET[m * 64 + 32 + quad * 8];
        eacc = __builtin_amdgcn_mfma_f32_16x16x32_bf16(a0, e0, eacc, 0, 0, 0);
        eacc = __builtin_amdgcn_mfma_f32_16x16x32_bf16(a1, e1, eacc, 0, 0, 0);
    }
    int srow = b * 64 + w * 16 + quad * 4;
#pragma unroll
    for (int nt = 0; nt < 8; ++nt) {
#pragma unroll
        for (int r = 0; r < 4; ++r) {
            int rr = srow + r;
            if (rr < NA) out[(size_t)rr * 128 + nt * 16 + m] = __float2bfloat16(acc[nt][r]);
        }
    }
    if (m < 4) {
#pragma unroll
        for (int r = 0; r < 4; ++r) {
            int rr = srow + r;
            if (rr < NA) elout[(size_t)rr * 4 + m] = eacc[r];
        }
    }
}

// MFMA res: hbuf = x_ag @ [Wres_gt|Wres_uav] + bias, fused er GEMVs. LDS-staged.
__global__ void res_k(const void* xa, const unsigned short* wrT,
                      const unsigned short* erT,
                      const void* bg, const void* bu,
                      float* elbase, bf16* hbuf, const int* flag) {
    int f32 = *flag;
    int b = blockIdx.x;
    __shared__ unsigned short Bt[256 * 72];  // 36 KB
    __shared__ float bl[256];
    int t = threadIdx.x;
    for (int i = t * 8; i < 256 * 64; i += 256 * 8) {
        short8 v = *(const short8*)(wrT + i);
        int n = i >> 6, k = i & 63;
        *(short8*)&Bt[n * 72 + k] = v;
    }
    bl[t] = (t < 128) ? ldf(bg, t, f32) : ldf(bu, t - 128, f32);
    __syncthreads();
    int lane = t & 63, w = t >> 6;
    int m = lane & 15, quad = lane >> 4;
    int row = b * 64 + w * 16 + m;
    int rowc = row < NA ? row : NA - 1;
    short8 a0 = ldfrag8(xa, (size_t)rowc * 64 + quad * 8, f32);
    short8 a1 = ldfrag8(xa, (size_t)rowc * 64 + 32 + quad * 8, f32);
    f32x4 acc[16];
#pragma unroll
    for (int nt = 0; nt < 16; ++nt) acc[nt] = (f32x4){0.f, 0.f, 0.f, 0.f};
#pragma unroll
    for (int nt = 0; nt < 16; ++nt) {
        short8 b0 = *(const short8*)&Bt[(nt * 16 + m) * 72 + quad * 8];
        short8 b1 = *(const short8*)&Bt[(nt * 16 + m) * 72 + 32 + quad * 8];
        acc[nt] = __builtin_amdgcn_mfma_f32_16x16x32_bf16(a0, b0, acc[nt], 0, 0, 0);
        acc[nt] = __builtin_amdgcn_mfma_f32_16x16x32_bf16(a1, b1, acc[nt], 0, 0, 0);
    }
    f32x4 eacc = (f32x4){0.f, 0.f, 0.f, 0.f};
    {
        short8 e0 = *(const short8*)&erT[m * 64 + quad * 8];
        short8 e1 = *(const short8*)&erT[m * 64 + 32 + quad * 8];
        eacc = __builtin_amdgcn_mfma_f32_16x16x32_bf16(a0, e0, eacc, 0, 0, 0);
        eacc = __builtin_amdgcn_mfma_f32_16x16x32_bf16(a1, e1, eacc, 0, 0, 0);
    }
    int srow = b * 64 + w * 16 + quad * 4;
#pragma unroll
    for (int nt = 0; nt < 16; ++nt) {
        int col = nt * 16 + m;
#pragma unroll
        for (int r = 0; r < 4; ++r) {
            int rr = srow + r;
            if (rr < NA)
                hbuf[(size_t)rr * 256 + col] = __float2bfloat16(acc[nt][r] + bl[col]);
        }
    }
    if (m < 8) {
        float* ero = (m < 4) ? (elbase + 200000) : (elbase + 600000);
        int mm = m & 3;
#pragma unroll
        for (int r = 0; r < 4; ++r) {
            int rr = srow + r;
            if (rr < NA) ero[(size_t)rr * 4 + mm] = eacc[r];
        }
    }
}

__global__ void scan1_k(const unsigned int* cnt, unsigned int* row, unsigned int* tops) {
    __shared__ unsigned int sh[256];
    int b = blockIdx.x, t = threadIdx.x;
    int base = b * 1024 + t * 4;
    unsigned int v[4];
    for (int j = 0; j < 4; ++j) v[j] = (base + j < 100000) ? cnt[base + j] : 0u;
    unsigned int s = v[0] + v[1] + v[2] + v[3];
    sh[t] = s;
    __syncthreads();
    for (int off = 1; off < 256; off <<= 1) {
        unsigned int x = (t >= off) ? sh[t - off] : 0u;
        __syncthreads();
        sh[t] += x;
        __syncthreads();
    }
    unsigned int run = sh[t] - s;
    for (int j = 0; j < 4; ++j) {
        if (base + j < 100000) row[base + j] = run;
        run += v[j];
    }
    if (t == 255) tops[b] = sh[255];
}

__global__ void scan2_k(unsigned int* tops, unsigned int* row) {
    __shared__ unsigned int sh[128];
    int t = threadIdx.x;
    unsigned int v = (t < 98) ? tops[t] : 0u;
    sh[t] = v;
    __syncthreads();
    for (int off = 1; off < 128; off <<= 1) {
        unsigned int x = (t >= off) ? sh[t - off] : 0u;
        __syncthreads();
        sh[t] += x;
        __syncthreads();
    }
    if (t < 98) tops[t] = sh[t] - v;
    if (t == 97) row[100000] = sh[97];
}

__global__ void scan3_k(unsigned int* row, const unsigned int* tops) {
    int b = blockIdx.x, t = threadIdx.x;
    unsigned int off = tops[b];
    for (int i = b * 1024 + t; i < b * 1024 + 1024; i += 256) {
        if (i < 100000) row[i] += off;
    }
}

// CSR scatter v3: ATOMIC-FREE. pos = row[dst] + rank[e] (rank captured during
// the histogram's atomicAdd in prep). Pure streaming: one 16B store per edge.
__global__ void scatter_k(const int* sg, const int* dg, const int* su, const int* du,
                          const float* elbase, const unsigned int* row,
                          const unsigned int* rank, uint4* recs) {
    int idx = blockIdx.x * 256 + threadIdx.x;
    if (idx >= 2 * NE) return;
    int g = idx >= NE;
    int e = idx - g * NE;
    int s = (g ? su : sg)[e];
    int d = (g ? du : dg)[e];
    const float4* el4 = (const float4*)(elbase + (g ? 400000 : 0));
    const float4* er4 = (const float4*)(elbase + (g ? 600000 : 200000));
    unsigned int pos = row[g * NA + d] + rank[idx];
    float4 l = el4[s], r = er4[d];
    uint4 rec;
    rec.x = (unsigned int)s;
    rec.y = pack_bf16x2(lrelu_exp(l.x + r.x), lrelu_exp(l.y + r.y));
    rec.z = pack_bf16x2(lrelu_exp(l.z + r.z), lrelu_exp(l.w + r.w));
    rec.w = 0u;
    recs[pos] = rec;
}

// gather v4: one wave per (dst, graph), TWO edges per wave iteration.
// Lanes 0-31 take even edges, 32-63 odd; each lane covers 4 cols via one
// uint2 (8B) fs load. Half-wave partials merged with shfl_xor(32) at row end.
// Fused residual + relu RMW on hbuf.
__global__ void gather_k(const unsigned int* row, const uint4* recs,
                         const bf16* fs, bf16* hbuf) {
    int wid = (blockIdx.x * 256 + threadIdx.x) >> 6;
    int lane = threadIdx.x & 63;
    if (wid >= 2 * NA) return;
    int g = wid / NA, d = wid - g * NA;
    int eh = lane >> 5;        // which edge of the pair
    int sl = lane & 31;        // cols c = sl*4 .. sl*4+3
    int h = sl >> 3;           // head for these cols
    int hsel = h >> 1, hodd = h & 1;
    unsigned int start = row[g * NA + d];
    unsigned int end   = row[g * NA + d + 1];
    const uint2* fsw2 = (const uint2*)(fs + (size_t)g * NA * 128);

    float denom = 0.f, a0 = 0.f, a1 = 0.f, a2 = 0.f, a3 = 0.f;
    unsigned int i = start;
    for (; i + 8 <= end; i += 8) {       // 4 pairs = 8 edges
        uint4 rr[4];
        uint2 uu[4];
#pragma unroll
        for (int j = 0; j < 4; ++j) rr[j] = recs[i + 2 * j + eh];
#pragma unroll
        for (int j = 0; j < 4; ++j) uu[j] = fsw2[(size_t)rr[j].x * 32 + sl];
#pragma unroll
        for (int j = 0; j < 4; ++j) {
            unsigned int pp = hsel ? rr[j].z : rr[j].y;
            float e = hodd ? hi_f(pp) : lo_f(pp);
            denom += e;
            a0 += lo_f(uu[j].x) * e;
            a1 += hi_f(uu[j].x) * e;
            a2 += lo_f(uu[j].y) * e;
            a3 += hi_f(uu[j].y) * e;
        }
    }
    for (; i + 2 <= end; i += 2) {       // single pair
        uint4 rc = recs[i + eh];
        uint2 u = fsw2[(size_t)rc.x * 32 + sl];
        unsigned int pp = hsel ? rc.z : rc.y;
        float e = hodd ? hi_f(pp) : lo_f(pp);
        denom += e;
        a0 += lo_f(u.x) * e;
        a1 += hi_f(u.x) * e;
        a2 += lo_f(u.y) * e;
        a3 += hi_f(u.y) * e;
    }
    if (i < end) {                       // odd tail: only eh==0 half contributes
        uint4 rc = recs[i];
        uint2 u = fsw2[(size_t)rc.x * 32 + sl];
        unsigned int pp = hsel ? rc.z : rc.y;
        float e = hodd ? hi_f(pp) : lo_f(pp);
        if (eh) e = 0.f;
        denom += e;
        a0 += lo_f(u.x) * e;
        a1 += hi_f(u.x) * e;
        a2 += lo_f(u.y) * e;
        a3 += hi_f(u.y) * e;
    }
    // merge the two half-wave partials (same dst row, same cols)
    denom += __shfl_xor(denom, 32, 64);
    a0 += __shfl_xor(a0, 32, 64);
    a1 += __shfl_xor(a1, 32, 64);
    a2 += __shfl_xor(a2, 32, 64);
    a3 += __shfl_xor(a3, 32, 64);
    if (eh == 0) {
        float inv = (end > start) ? 1.f / denom : 0.f;
        a0 *= inv; a1 *= inv; a2 *= inv; a3 *= inv;
        uint2* hp = (uint2*)(hbuf + (size_t)d * 256 + g * 128) + sl;
        uint2 rv = *hp;
        float v0 = a0 + lo_f(rv.x);
        float v1 = a1 + hi_f(rv.x);
        float v2 = a2 + lo_f(rv.y);
        float v3 = a3 + hi_f(rv.y);
        v0 = v0 > 0.f ? v0 : 0.f;
        v1 = v1 > 0.f ? v1 : 0.f;
        v2 = v2 > 0.f ? v2 : 0.f;
        v3 = v3 > 0.f ? v3 : 0.f;
        uint2 o;
        o.x = pack_bf16x2(v0, v1);
        o.y = pack_bf16x2(v2, v3);
        *hp = o;
    }
}

// MFMA final: out = relu(hbuf @ W_f + b_f). LDS-staged per 64-k chunk.
__global__ void final_k(const bf16* hbuf, const unsigned short* wfT,
                        const void* bfp, void* outp, const int* flag) {
    int f32 = *flag;
    int b = blockIdx.x;
    __shared__ unsigned short Bt[128 * 72];  // 18 KB
    __shared__ float bl[128];
    int t = threadIdx.x;
    if (t < 128) bl[t] = ldf(bfp, t, f32);
    int lane = t & 63, w = t >> 6;
    int m = lane & 15, quad = lane >> 4;
    int row = b * 64 + w * 16 + m;
    int rowc = row < NA ? row : NA - 1;
    f32x4 acc[8];
#pragma unroll
    for (int nt = 0; nt < 8; ++nt) acc[nt] = (f32x4){0.f, 0.f, 0.f, 0.f};
    for (int kc = 0; kc < 4; ++kc) {
        __syncthreads();
        for (int i = t * 8; i < 128 * 64; i += 256 * 8) {
            int n = i >> 6, k = i & 63;
            short8 v = *(const short8*)(wfT + (size_t)n * 256 + kc * 64 + k);
            *(short8*)&Bt[n * 72 + k] = v;
        }
        __syncthreads();
        short8 a0 = *(const short8*)((const unsigned short*)hbuf +
                                     (size_t)rowc * 256 + kc * 64 + quad * 8);
        short8 a1 = *(const short8*)((const unsigned short*)hbuf +
                                     (size_t)rowc * 256 + kc * 64 + 32 + quad * 8);
#pragma unroll
        for (int nt = 0; nt < 8; ++nt) {
            short8 b0 = *(const short8*)&Bt[(nt * 16 + m) * 72 + quad * 8];
            short8 b1 = *(const short8*)&Bt[(nt * 16 + m) * 72 + 32 + quad * 8];
            acc[nt] = __builtin_amdgcn_mfma_f32_16x16x32_bf16(a0, b0, acc[nt], 0, 0, 0);
            acc[nt] = __builtin_amdgcn_mfma_f32_16x16x32_bf16(a1, b1, acc[nt], 0, 0, 0);
        }
    }
    int srow = b * 64 + w * 16 + quad * 4;
#pragma unroll
    for (int nt = 0; nt < 8; ++nt) {
        int col = nt * 16 + m;
        float bv = bl[col];
#pragma unroll
        for (int r = 0; r < 4; ++r) {
            int rr = srow + r;
            if (rr < NA) {
                float v = acc[nt][r] + bv;
                v = v > 0.f ? v : 0.f;
                if (f32) ((float*)outp)[(size_t)rr * 128 + col] = v;
                else ((bf16*)outp)[(size_t)rr * 128 + col] = __float2bfloat16(v);
            }
        }
    }
}

extern "C" void kernel_launch(void* const* d_in, const int* in_sizes, int n_in,
                              void* d_out, int out_size, void* d_ws, size_t ws_size,
                              hipStream_t stream) {
    const void* x_gt     = d_in[0];
    const void* x_uav    = d_in[1];
    const void* x_ag     = d_in[2];
    const int*  src_gt   = (const int*)d_in[3];
    const int*  dst_gt   = (const int*)d_in[4];
    const int*  src_uav  = (const int*)d_in[5];
    const int*  dst_uav  = (const int*)d_in[6];
    const void* Wsrc_gt  = d_in[7];
    const void* Wdst_gt  = d_in[8];
    const void* al_gt    = d_in[9];
    const void* ar_gt    = d_in[10];
    const void* Wres_gt  = d_in[11];
    const void* b_gt     = d_in[12];
    const void* Wsrc_uav = d_in[13];
    const void* Wdst_uav = d_in[14];
    const void* al_uav   = d_in[15];
    const void* ar_uav   = d_in[16];
    const void* Wres_uav = d_in[17];
    const void* b_uav    = d_in[18];
    const void* W_f      = d_in[19];
    const void* b_f      = d_in[20];

    char* wsb = (char*)d_ws;
    bf16* hbuf = (bf16*)(wsb + HBUF_B);
    bf16* fs = (bf16*)(wsb + FS_B);
    float* el = (float*)(wsb + EL_B);
    uint4* recs = (uint4*)(wsb + RECS_B);
    unsigned int* cnt = (unsigned int*)(wsb + CNT_B);
    unsigned int* row = (unsigned int*)(wsb + ROW_B);
    unsigned int* tops = (unsigned int*)(wsb + TOPS_B);
    int* flag = (int*)(wsb + FLAG_B);
    unsigned short* wsT_gt = (unsigned short*)(wsb + WST_GT_B);
    unsigned short* wsT_uav = (unsigned short*)(wsb + WST_UAV_B);
    unsigned short* wrT = (unsigned short*)(wsb + WRT_B);
    unsigned short* wfT = (unsigned short*)(wsb + WFT_B);
    unsigned short* elT_gt = (unsigned short*)(wsb + ELT_GT_B);
    unsigned short* elT_uav = (unsigned short*)(wsb + ELT_UAV_B);
    unsigned short* erT = (unsigned short*)(wsb + ERT_B);
    unsigned int* rank = (unsigned int*)(wsb + RANK_B);

    if (ws_size < (size_t)WS_BYTES) {
        hipMemsetAsync(d_out, 0x42, (size_t)out_size * 2, stream);
        return;
    }

    long sent = (long)out_size / 2 - 1;

    hipMemsetAsync(cnt, 0, 100000 * 4, stream);
    HeteroVisionConv_29703993819529_kernel<<<21 + 1172, 256, 0, stream>>>(
        x_gt, Wsrc_gt, al_gt, Wdst_gt, ar_gt, Wsrc_uav, al_uav, Wdst_uav, ar_uav,
        Wres_gt, Wres_uav, W_f, dst_gt, dst_uav, cnt, rank,
        wsT_gt, wsT_uav, wrT, wfT, elT_gt, elT_uav, erT,
        flag, (unsigned int*)d_out, sent);
    node_fs_k<<<1564, 256, 0, stream>>>(x_gt, x_uav, wsT_gt, wsT_uav,
                                        elT_gt, elT_uav, el, fs, flag);
    res_k<<<782, 256, 0, stream>>>(x_ag, wrT, erT, b_gt, b_uav, el, hbuf, flag);
    scan1_k<<<98, 256, 0, stream>>>(cnt, row, tops);
    scan2_k<<<1, 128, 0, stream>>>(tops, row);
    scan3_k<<<98, 256, 0, stream>>>(row, tops);
    scatter_k<<<4688, 256, 0, stream>>>(src_gt, dst_gt, src_uav, dst_uav,
                                        el, row, rank, recs);
    gather_k<<<25000, 256, 0, stream>>>(row, recs, fs, hbuf);
    final_k<<<782, 256, 0, stream>>>(hbuf, wfT, b_f, d_out, flag);
}